// Round 7
// baseline (854.655 us; speedup 1.0000x reference)
//
#include <hip/hip_runtime.h>
#include <cstdint>
#include <cstddef>

// ---------------------------------------------------------------------------
// APPNP: h = MLP(x); h0 = h; 10x { h = 0.9 * A_w @ h + 0.1 * h0 }
// R10: quarter-phased gather for L2 residency. Edges sorted by (row, colQ)
// where colQ = col>>14 (4 quarters of 16K nodes = 2 MB state each). Prop
// sweeps quarters in order (all waves chip-wide in rough phase), so each
// XCD's L2 only holds ~1.7 MB of gather lines per phase -> capacity misses
// eliminated, only compulsory (~43%) go to L3. Inner loop = R8's proven
// pair-gather (R9's wide gather regressed: CU miss pipeline saturated, and
// 24-shfl reduce added serial DS work -> reverted). cnt2 (= per-(row,Q)
// segment starts) now persists until prop in a dedicated 1 MB region.
// ---------------------------------------------------------------------------

#define N_NODES   65536
#define N_EDGES   1048576
#define IN_DIM    500
#define IN_PAD    512
#define HID_DIM   256
#define OUT_DIM   64
#define K_STEPS   10

#define NPW   8      // nodes per wave in prop
#define CAPW  608    // per-wave LDS edge capacity (int2) -> 19456 B/block
#define NCHUNK 4     // counting-sort chunks = col quarters (colQ = col >> 14)

typedef _Float16 half8 __attribute__((ext_vector_type(8)));
typedef float    f32x4 __attribute__((ext_vector_type(4)));

// ---- workspace layout (bytes) ---------------------------------------------
#define XB_OFF    0ULL                     // 67108864 (f16 x, K-padded)
#define HA_OFF    0ULL                     // bf16 prop ping (8 MB, reuses xb)
#define HB_OFF    33554432ULL              // bf16 prop pong (8 MB)
#define H1_OFF    67108864ULL              // 33554432 (f16)
#define H0_OFF    67108864ULL              // bf16 h0 (8 MB, reuses h1)
#define H2_OFF    100663296ULL             // 33554432 (f16)
// CSR-build scratch overlapping H2 (consumed before GEMM2 writes h2):
#define RANK_OFF  104857600ULL             // E*4 = 4194304
#define TOT_OFF   109051904ULL             // N*4
#define W1T_OFF   134217728ULL             // 262144
#define W2T_OFF   134479872ULL             // 131072
#define W3T_OFF   134610944ULL             // 32768
#define ROWP_OFF  134643712ULL             // (N+1)*4
#define EDG_OFF   135430400ULL             // E*8 (int2: col, w-bits f32)
#define CNT2_OFF  143819008ULL             // 4*65536*4 = 1048576 (lives
//   until prop: quarter segment starts). end 144867584 (~138.2 MiB)

__device__ __forceinline__ void gload_lds16(const void* g, void* l) {
  __builtin_amdgcn_global_load_lds(
      (const __attribute__((address_space(1))) void*)g,
      (__attribute__((address_space(3))) void*)l, 16, 0, 0);
}

__device__ __forceinline__ unsigned short f2bf_rne(float f) {
  unsigned u = __float_as_uint(f);
  u += 0x7fffu + ((u >> 16) & 1u);
  return (unsigned short)(u >> 16);
}
__device__ __forceinline__ float uaf(int u) {
  return __uint_as_float((unsigned)u);
}
__device__ __forceinline__ float lo16(unsigned v) {
  return __uint_as_float(v << 16);
}
__device__ __forceinline__ float hi16(unsigned v) {
  return __uint_as_float(v & 0xffff0000u);
}

// ---------------------------------------------------------------------------
// f16 MFMA GEMM. OMODE: 0 = f16 out, 1 = bf16 out (ushort), 2 = f32 out.
// ---------------------------------------------------------------------------
template <int TM, int TN, int WM, int WN, bool RELU, int OMODE>
__global__ __launch_bounds__(256)
void gemm_kernel(const _Float16* __restrict__ A, const _Float16* __restrict__ B,
                 const float* __restrict__ bias, void* __restrict__ Cout,
                 int M, int Nn, int K) {
  static_assert((TM * 8) % 256 == 0 && (TN * 8) % 256 == 0, "tile");
  __shared__ uint4 As[TM * 8];
  __shared__ uint4 Bs[TN * 8];
  const int t    = threadIdx.x;
  const int lane = t & 63;
  const int wave = t >> 6;
  const int wm   = wave / WN;
  const int wn   = wave % WN;
  const int row0 = blockIdx.x * TM;
  const int col0 = blockIdx.y * TN;
  const int l15  = lane & 15;
  const int lq   = lane >> 4;

  f32x4 acc[4][4];
#pragma unroll
  for (int i = 0; i < 4; ++i)
#pragma unroll
    for (int j = 0; j < 4; ++j) acc[i][j] = (f32x4){0.f, 0.f, 0.f, 0.f};

  for (int k0 = 0; k0 < K; k0 += 64) {
#pragma unroll
    for (int i = 0; i < (TM * 8) / 256; ++i) {
      const int c = i * 256 + wave * 64 + lane;
      const int q = c / TM;
      const int r = c % TM;
      gload_lds16(A + (size_t)(row0 + r) * K + (k0 + q * 8),
                  As + i * 256 + wave * 64);
    }
#pragma unroll
    for (int i = 0; i < (TN * 8) / 256; ++i) {
      const int c = i * 256 + wave * 64 + lane;
      const int q = c / TN;
      const int r = c % TN;
      gload_lds16(B + (size_t)(col0 + r) * K + (k0 + q * 8),
                  Bs + i * 256 + wave * 64);
    }
    __syncthreads();
#pragma unroll
    for (int kk = 0; kk < 2; ++kk) {
      const int qa = kk * 4 + lq;
      half8 af[4], bfr[4];
#pragma unroll
      for (int mt = 0; mt < 4; ++mt)
        af[mt] = *((const half8*)(As + (qa * TM + wm * 64 + mt * 16 + l15)));
#pragma unroll
      for (int nt = 0; nt < 4; ++nt)
        bfr[nt] = *((const half8*)(Bs + (qa * TN + wn * 64 + nt * 16 + l15)));
#pragma unroll
      for (int mt = 0; mt < 4; ++mt)
#pragma unroll
        for (int nt = 0; nt < 4; ++nt)
          acc[mt][nt] = __builtin_amdgcn_mfma_f32_16x16x32_f16(
              af[mt], bfr[nt], acc[mt][nt], 0, 0, 0);
    }
    __syncthreads();
  }

#pragma unroll
  for (int mt = 0; mt < 4; ++mt) {
#pragma unroll
    for (int nt = 0; nt < 4; ++nt) {
      const int col = col0 + wn * 64 + nt * 16 + l15;
      const float bv = bias[col];
#pragma unroll
      for (int r = 0; r < 4; ++r) {
        const int row = row0 + wm * 64 + mt * 16 + lq * 4 + r;
        float v = acc[mt][nt][r] + bv;
        if (RELU) v = fmaxf(v, 0.f);
        if (OMODE == 0)
          ((_Float16*)Cout)[(size_t)row * Nn + col] = (_Float16)v;
        else if (OMODE == 1)
          ((unsigned short*)Cout)[(size_t)row * Nn + col] = f2bf_rne(v);
        else
          ((float*)Cout)[(size_t)row * Nn + col] = v;
      }
    }
  }
}

// ---- cast x (fp32 MxK) -> f16 Mx512, zero-padded ---------------------------
__global__ void cast_x_kernel(const float* __restrict__ x,
                              _Float16* __restrict__ xb) {
  const int c = blockIdx.x * blockDim.x + threadIdx.x;
  if (c >= N_NODES * (IN_PAD / 8)) return;
  const int row = c >> 6;
  const int c8  = (c & 63) << 3;
  half8 o;
  if (c8 + 8 <= IN_DIM) {
    const float4* p = (const float4*)(x + (size_t)row * IN_DIM + c8);
    const float4 a = p[0], b = p[1];
    o[0] = (_Float16)a.x; o[1] = (_Float16)a.y;
    o[2] = (_Float16)a.z; o[3] = (_Float16)a.w;
    o[4] = (_Float16)b.x; o[5] = (_Float16)b.y;
    o[6] = (_Float16)b.z; o[7] = (_Float16)b.w;
  } else {
#pragma unroll
    for (int j = 0; j < 8; ++j) {
      const float v = (c8 + j < IN_DIM) ? x[(size_t)row * IN_DIM + c8 + j] : 0.f;
      o[j] = (_Float16)v;
    }
  }
  *(half8*)(xb + (size_t)c * 8) = o;
}

// ---- cast + transpose weight: W[K,N] fp32 -> Wt[N,Kpad] f16 ----------------
__global__ void cast_w_kernel(const float* __restrict__ W,
                              _Float16* __restrict__ Wt, int K, int Kpad,
                              int Nn) {
  const int idx = blockIdx.x * blockDim.x + threadIdx.x;
  if (idx >= Nn * Kpad) return;
  const int n = idx / Kpad;
  const int k = idx % Kpad;
  const float v = (k < K) ? W[(size_t)k * Nn + n] : 0.f;
  Wt[idx] = (_Float16)v;
}

// ---- CSR build: counting sort by (row, colQ) -------------------------------
// key chunk = col quarter (col>>14): edges land row-major, quarter-major
// within row. Contention per (colQ,row) slot avg = 4 -> fine.
__global__ void hist2_kernel(const int* __restrict__ row,
                             const int* __restrict__ col,
                             int* __restrict__ cnt2, int* __restrict__ rank,
                             int E) {
  const int e = blockIdx.x * blockDim.x + threadIdx.x;
  if (e < E)
    rank[e] = atomicAdd(&cnt2[(col[e] >> 14) * N_NODES + row[e]], 1);
}

__global__ void scan_tot_kernel(const int* __restrict__ cnt2,
                                int* __restrict__ tot) {
  const int r = blockIdx.x * blockDim.x + threadIdx.x;
  int s = 0;
#pragma unroll
  for (int c = 0; c < NCHUNK; ++c) s += cnt2[c * N_NODES + r];
  tot[r] = s;
}

// single-block exclusive scan of tot -> rowptr
__global__ void scan_kernel(const int4* __restrict__ counts4,
                            int* __restrict__ rowptr) {
  __shared__ int part[1024];
  const int t = threadIdx.x;
  const int base = t * 16;  // int4 units; 64 ints per thread
  int4 c[16];
  int s = 0;
#pragma unroll
  for (int i = 0; i < 16; ++i) {
    c[i] = counts4[base + i];
    s += c[i].x + c[i].y + c[i].z + c[i].w;
  }
  part[t] = s;
  __syncthreads();
  for (int off = 1; off < 1024; off <<= 1) {
    const int v = (t >= off) ? part[t - off] : 0;
    __syncthreads();
    part[t] += v;
    __syncthreads();
  }
  int run = (t == 0) ? 0 : part[t - 1];
#pragma unroll
  for (int i = 0; i < 16; ++i) {
    int4 r;
    r.x = run; run += c[i].x;
    r.y = run; run += c[i].y;
    r.z = run; run += c[i].z;
    r.w = run; run += c[i].w;
    ((int4*)rowptr)[base + i] = r;
  }
  if (t == 1023) rowptr[N_NODES] = run;
}

// cnt2[c][r] <- rowptr[r] + prefix_c(cnt2[.][r])  (in place, per-column).
// After this, cnt2[q][r] = global start of quarter-q segment of row r.
__global__ void chunkbase_kernel(int* __restrict__ cnt2,
                                 const int* __restrict__ rowptr) {
  const int r = blockIdx.x * blockDim.x + threadIdx.x;
  int run = rowptr[r];
#pragma unroll
  for (int c = 0; c < NCHUNK; ++c) {
    const int t = cnt2[c * N_NODES + r];
    cnt2[c * N_NODES + r] = run;
    run += t;
  }
}

// atomic-free scatter: pos = quarter base + rank
__global__ void scatter2_kernel(const int* __restrict__ row,
                                const int* __restrict__ col,
                                const float* __restrict__ w,
                                const int* __restrict__ rank,
                                const int* __restrict__ cbase,
                                int2* __restrict__ edges, int E) {
  const int e = blockIdx.x * blockDim.x + threadIdx.x;
  if (e < E) {
    const int pos = cbase[(col[e] >> 14) * N_NODES + row[e]] + rank[e];
    edges[pos] = make_int2(col[e], __float_as_int(w[e]));
  }
}

// ---- propagation: quarter-phased pair-gather -------------------------------
// Quarter-outer, node-inner: all waves sweep source-node quarters (2 MB of
// state each) in the same order -> per-XCD L2 gather working set ~1.7 MB ->
// capacity misses gone. Inner loop = R8 pair-gather: lanes 0-31 even edge,
// 32-63 odd edge, each lane loads bf16x2; merge via shfl_xor(32) at end.
// rq register: lanes 0..31 = qstart[q=lane>>3][node0+(lane&7)],
// lane 32 = rowptr[node0+8].
template <bool OUT_F32>
__global__ __launch_bounds__(256)
void prop_step(const unsigned short* __restrict__ hin,
               const unsigned short* __restrict__ h0,
               void* __restrict__ hout, const int* __restrict__ rowptr,
               const int* __restrict__ qstart,
               const int2* __restrict__ edges) {
  __shared__ int2 eb[4][CAPW];
  const int wave = threadIdx.x >> 6;
  const int lane = threadIdx.x & 63;
  const int half = lane >> 5;
  const int lp   = lane & 31;
  const int node0 = (blockIdx.x * 4 + wave) * NPW;
  const unsigned* __restrict__ hin32 = (const unsigned*)hin;
  const unsigned* __restrict__ h032  = (const unsigned*)h0;

  int rq = 0;
  if (lane < 32)
    rq = qstart[(lane >> 3) * N_NODES + node0 + (lane & 7)];
  else if (lane == 32)
    rq = rowptr[node0 + NPW];
  const int beg = __shfl(rq, 0);
  const int nE  = __shfl(rq, 32) - beg;
  int2* __restrict__ ebw = eb[wave];

  const bool fast = (nE <= CAPW);
  if (fast) {
    for (int i = lane; i < nE; i += 64) ebw[i] = edges[beg + i];
    __builtin_amdgcn_s_waitcnt(0);  // drain vm+lgkm: staging visible wave-wide
  }

  float ax[NPW], ay[NPW];
#pragma unroll
  for (int i = 0; i < NPW; ++i) { ax[i] = 0.f; ay[i] = 0.f; }

  for (int q = 0; q < 4; ++q) {
    for (int i = 0; i < NPW; ++i) {
      const int sb = __shfl(rq, q * 8 + i) - beg;
      const int se = (q < 3) ? (__shfl(rq, q * 8 + 8 + i) - beg)
                   : ((i < NPW - 1) ? (__shfl(rq, i + 1) - beg) : nE);
      float a0 = 0.f, a1 = 0.f, b0 = 0.f, b1 = 0.f;
      int j = sb;
      if (fast) {
        for (; j + 4 <= se; j += 4) {  // 2 pair-loads in flight
          const int2 e0 = ebw[j + half];
          const int2 e1 = ebw[j + 2 + half];
          const unsigned v0 = hin32[(e0.x << 5) | lp];
          const unsigned v1 = hin32[(e1.x << 5) | lp];
          const float w0 = uaf(e0.y), w1 = uaf(e1.y);
          a0 = fmaf(w0, lo16(v0), a0); a1 = fmaf(w0, hi16(v0), a1);
          b0 = fmaf(w1, lo16(v1), b0); b1 = fmaf(w1, hi16(v1), b1);
        }
        for (; j + 2 <= se; j += 2) {
          const int2 e = ebw[j + half];
          const unsigned v = hin32[(e.x << 5) | lp];
          const float w = uaf(e.y);
          a0 = fmaf(w, lo16(v), a0); a1 = fmaf(w, hi16(v), a1);
        }
        if (j < se) {  // odd leftover: lower half contributes
          const int2 e = ebw[j];
          const unsigned v = hin32[(e.x << 5) | lp];
          const float w = half ? 0.f : uaf(e.y);
          a0 = fmaf(w, lo16(v), a0); a1 = fmaf(w, hi16(v), a1);
        }
      } else {  // degenerate degree distribution: direct-global path
        for (; j < se; j += 2) {
          const int idx = j + half;
          const int2 e = edges[beg + (idx < se ? idx : se - 1)];
          const float w = (idx < se) ? uaf(e.y) : 0.f;
          const unsigned v = hin32[(e.x << 5) | lp];
          a0 = fmaf(w, lo16(v), a0); a1 = fmaf(w, hi16(v), a1);
        }
      }
      ax[i] += a0 + b0;
      ay[i] += a1 + b1;
    }
  }

#pragma unroll
  for (int i = 0; i < NPW; ++i) {
    float sx = ax[i];
    float sy = ay[i];
    sx += __shfl_xor(sx, 32);  // merge even/odd edge halves
    sy += __shfl_xor(sy, 32);
    const int o32 = ((node0 + i) << 5) | lp;
    const unsigned h0v = h032[o32];
    const float r0 = 0.9f * sx + 0.1f * lo16(h0v);
    const float r1 = 0.9f * sy + 0.1f * hi16(h0v);
    if (half == 0) {
      if (OUT_F32) {
        ((float2*)hout)[o32] = make_float2(r0, r1);
      } else {
        ((unsigned*)hout)[o32] =
            (unsigned)f2bf_rne(r0) | ((unsigned)f2bf_rne(r1) << 16);
      }
    }
  }
}

// ---------------------------------------------------------------------------
extern "C" void kernel_launch(void* const* d_in, const int* in_sizes, int n_in,
                              void* d_out, int out_size, void* d_ws,
                              size_t ws_size, hipStream_t stream) {
  const float* x  = (const float*)d_in[0];
  const float* W1 = (const float*)d_in[1];
  const float* b1 = (const float*)d_in[2];
  const float* W2 = (const float*)d_in[3];
  const float* b2 = (const float*)d_in[4];
  const float* W3 = (const float*)d_in[5];
  const float* b3 = (const float*)d_in[6];
  const float* ew = (const float*)d_in[7];
  const int* erow = (const int*)d_in[8];
  const int* ecol = (const int*)d_in[9];

  char* ws = (char*)d_ws;
  _Float16* xb  = (_Float16*)(ws + XB_OFF);
  _Float16* h1  = (_Float16*)(ws + H1_OFF);
  _Float16* h2  = (_Float16*)(ws + H2_OFF);
  _Float16* w1t = (_Float16*)(ws + W1T_OFF);
  _Float16* w2t = (_Float16*)(ws + W2T_OFF);
  _Float16* w3t = (_Float16*)(ws + W3T_OFF);
  unsigned short* h0b = (unsigned short*)(ws + H0_OFF);
  unsigned short* hAb = (unsigned short*)(ws + HA_OFF);
  unsigned short* hBb = (unsigned short*)(ws + HB_OFF);
  int* rowp     = (int*)(ws + ROWP_OFF);
  int* cnt2     = (int*)(ws + CNT2_OFF);
  int* rankb    = (int*)(ws + RANK_OFF);
  int* tot      = (int*)(ws + TOT_OFF);
  int2* edges   = (int2*)(ws + EDG_OFF);
  float* outp   = (float*)d_out;

  // --- CSR build: counting sort by (row, colQ) ------------------------------
  hipMemsetAsync(cnt2, 0, NCHUNK * N_NODES * sizeof(int), stream);
  hist2_kernel<<<N_EDGES / 256, 256, 0, stream>>>(erow, ecol, cnt2, rankb,
                                                  N_EDGES);
  scan_tot_kernel<<<N_NODES / 256, 256, 0, stream>>>(cnt2, tot);
  scan_kernel<<<1, 1024, 0, stream>>>((const int4*)tot, rowp);
  chunkbase_kernel<<<N_NODES / 256, 256, 0, stream>>>(cnt2, rowp);
  scatter2_kernel<<<N_EDGES / 256, 256, 0, stream>>>(erow, ecol, ew, rankb,
                                                     cnt2, edges, N_EDGES);

  // --- MLP ------------------------------------------------------------------
  cast_x_kernel<<<(N_NODES * (IN_PAD / 8)) / 256, 256, 0, stream>>>(x, xb);
  cast_w_kernel<<<(HID_DIM * IN_PAD) / 256, 256, 0, stream>>>(W1, w1t, IN_DIM,
                                                              IN_PAD, HID_DIM);
  cast_w_kernel<<<(HID_DIM * HID_DIM) / 256, 256, 0, stream>>>(
      W2, w2t, HID_DIM, HID_DIM, HID_DIM);
  cast_w_kernel<<<(OUT_DIM * HID_DIM) / 256, 256, 0, stream>>>(
      W3, w3t, HID_DIM, HID_DIM, OUT_DIM);

  gemm_kernel<128, 128, 2, 2, true, 0>
      <<<dim3(N_NODES / 128, HID_DIM / 128), 256, 0, stream>>>(
          xb, w1t, b1, h1, N_NODES, HID_DIM, IN_PAD);
  gemm_kernel<128, 128, 2, 2, true, 0>
      <<<dim3(N_NODES / 128, HID_DIM / 128), 256, 0, stream>>>(
          h1, w2t, b2, h2, N_NODES, HID_DIM, HID_DIM);
  gemm_kernel<256, 64, 4, 1, false, 1>
      <<<dim3(N_NODES / 256, 1), 256, 0, stream>>>(h2, w3t, b3, h0b, N_NODES,
                                                   OUT_DIM, HID_DIM);

  // --- K=10 propagation (bf16 state; last step writes f32 to d_out) --------
  for (int s = 0; s < K_STEPS - 1; ++s) {
    const unsigned short* hin = (s == 0) ? h0b : ((s - 1) & 1 ? hBb : hAb);
    unsigned short* hout = (s & 1) ? hBb : hAb;
    prop_step<false><<<N_NODES / (4 * NPW), 256, 0, stream>>>(
        hin, h0b, hout, rowp, cnt2, edges);
  }
  prop_step<true><<<N_NODES / (4 * NPW), 256, 0, stream>>>(
      (K_STEPS - 2) & 1 ? hBb : hAb, h0b, outp, rowp, cnt2, edges);
}

// Round 9
// 628.099 us; speedup vs baseline: 1.3607x; 1.3607x over previous
//
#include <hip/hip_runtime.h>
#include <cstdint>
#include <cstddef>

// ---------------------------------------------------------------------------
// APPNP: h = MLP(x); h0 = h; 10x { h = 0.9 * A_w @ h + 0.1 * h0 }
// R11b = R8 base (best: 642us) + GEMM1 fused with x-cast: TM=128 x TN=256
// (single col-pass: x read ONCE), A staged f32 via async global_load_lds,
// f32->f16 at fragment read via v_cvt_pkrtz (overlaps MFMA). cast_x
// eliminated. Prop = R8 pair-gather exactly.
// (R11a compile fix: cvt_pkrtz returns __fp16x2, not _Float16x2.)
// ---------------------------------------------------------------------------

#define N_NODES   65536
#define N_EDGES   1048576
#define IN_DIM    500
#define IN_PAD    512
#define HID_DIM   256
#define OUT_DIM   64
#define K_STEPS   10

#define NPW   8      // nodes per wave in prop
#define CAPW  608    // per-wave LDS edge capacity (int2) -> 19456 B/block
#define NCHUNK 16    // counting-sort chunks (chunk = e >> 16)

typedef _Float16 half8 __attribute__((ext_vector_type(8)));
typedef __fp16   fp16x2 __attribute__((ext_vector_type(2)));
typedef float    f32x4 __attribute__((ext_vector_type(4)));

// ---- workspace layout (bytes) ---------------------------------------------
#define HA_OFF    0ULL                     // bf16 prop ping (8 MB)
#define HB_OFF    33554432ULL              // bf16 prop pong (8 MB)
#define H1_OFF    67108864ULL              // 33554432 (f16)
#define H0_OFF    67108864ULL              // bf16 h0 (8 MB, reuses h1)
#define H2_OFF    100663296ULL             // 33554432 (f16)
// CSR-build scratch lives in the H2 region (free until GEMM2 runs):
#define CNT2_OFF  100663296ULL             // 16*65536*4 = 4194304
#define RANK_OFF  104857600ULL             // E*4 = 4194304
#define TOT_OFF   109051904ULL             // N*4
#define W1T_OFF   134217728ULL             // 262144
#define W2T_OFF   134479872ULL             // 131072
#define W3T_OFF   134610944ULL             // 32768
#define ROWP_OFF  134643712ULL             // (N+1)*4
#define EDG_OFF   135430400ULL             // E*8 (int2: col, w-bits f32)
// end 143819008 (~137 MiB)

__device__ __forceinline__ void gload_lds16(const void* g, void* l) {
  __builtin_amdgcn_global_load_lds(
      (const __attribute__((address_space(1))) void*)g,
      (__attribute__((address_space(3))) void*)l, 16, 0, 0);
}

__device__ __forceinline__ unsigned short f2bf_rne(float f) {
  unsigned u = __float_as_uint(f);
  u += 0x7fffu + ((u >> 16) & 1u);
  return (unsigned short)(u >> 16);
}
__device__ __forceinline__ float uaf(unsigned u) {
  return __uint_as_float(u);
}
__device__ __forceinline__ float lo16(unsigned v) {
  return __uint_as_float(v << 16);
}
__device__ __forceinline__ float hi16(unsigned v) {
  return __uint_as_float(v & 0xffff0000u);
}

// ---------------------------------------------------------------------------
// f16 MFMA GEMM. OMODE: 0 = f16 out, 1 = bf16 out (ushort), 2 = f32 out.
// ---------------------------------------------------------------------------
template <int TM, int TN, int WM, int WN, bool RELU, int OMODE>
__global__ __launch_bounds__(256)
void gemm_kernel(const _Float16* __restrict__ A, const _Float16* __restrict__ B,
                 const float* __restrict__ bias, void* __restrict__ Cout,
                 int M, int Nn, int K) {
  static_assert((TM * 8) % 256 == 0 && (TN * 8) % 256 == 0, "tile");
  __shared__ uint4 As[TM * 8];
  __shared__ uint4 Bs[TN * 8];
  const int t    = threadIdx.x;
  const int lane = t & 63;
  const int wave = t >> 6;
  const int wm   = wave / WN;
  const int wn   = wave % WN;
  const int row0 = blockIdx.x * TM;
  const int col0 = blockIdx.y * TN;
  const int l15  = lane & 15;
  const int lq   = lane >> 4;

  f32x4 acc[4][4];
#pragma unroll
  for (int i = 0; i < 4; ++i)
#pragma unroll
    for (int j = 0; j < 4; ++j) acc[i][j] = (f32x4){0.f, 0.f, 0.f, 0.f};

  for (int k0 = 0; k0 < K; k0 += 64) {
#pragma unroll
    for (int i = 0; i < (TM * 8) / 256; ++i) {
      const int c = i * 256 + wave * 64 + lane;
      const int q = c / TM;
      const int r = c % TM;
      gload_lds16(A + (size_t)(row0 + r) * K + (k0 + q * 8),
                  As + i * 256 + wave * 64);
    }
#pragma unroll
    for (int i = 0; i < (TN * 8) / 256; ++i) {
      const int c = i * 256 + wave * 64 + lane;
      const int q = c / TN;
      const int r = c % TN;
      gload_lds16(B + (size_t)(col0 + r) * K + (k0 + q * 8),
                  Bs + i * 256 + wave * 64);
    }
    __syncthreads();
#pragma unroll
    for (int kk = 0; kk < 2; ++kk) {
      const int qa = kk * 4 + lq;
      half8 af[4], bfr[4];
#pragma unroll
      for (int mt = 0; mt < 4; ++mt)
        af[mt] = *((const half8*)(As + (qa * TM + wm * 64 + mt * 16 + l15)));
#pragma unroll
      for (int nt = 0; nt < 4; ++nt)
        bfr[nt] = *((const half8*)(Bs + (qa * TN + wn * 64 + nt * 16 + l15)));
#pragma unroll
      for (int mt = 0; mt < 4; ++mt)
#pragma unroll
        for (int nt = 0; nt < 4; ++nt)
          acc[mt][nt] = __builtin_amdgcn_mfma_f32_16x16x32_f16(
              af[mt], bfr[nt], acc[mt][nt], 0, 0, 0);
    }
    __syncthreads();
  }

#pragma unroll
  for (int mt = 0; mt < 4; ++mt) {
#pragma unroll
    for (int nt = 0; nt < 4; ++nt) {
      const int col = col0 + wn * 64 + nt * 16 + l15;
      const float bv = bias[col];
#pragma unroll
      for (int r = 0; r < 4; ++r) {
        const int row = row0 + wm * 64 + mt * 16 + lq * 4 + r;
        float v = acc[mt][nt][r] + bv;
        if (RELU) v = fmaxf(v, 0.f);
        if (OMODE == 0)
          ((_Float16*)Cout)[(size_t)row * Nn + col] = (_Float16)v;
        else if (OMODE == 1)
          ((unsigned short*)Cout)[(size_t)row * Nn + col] = f2bf_rne(v);
        else
          ((float*)Cout)[(size_t)row * Nn + col] = v;
      }
    }
  }
}

// ---------------------------------------------------------------------------
// GEMM1 fused with x cast. A = x (f32, row stride 500), staged as f32 into
// LDS via async global_load_lds (16B = 4 f32 per slot), converted to f16 at
// fragment-read with v_cvt_pkrtz. TM=128, TN=256 (single col pass -> x read
// exactly once). K tail: kb>=500 clamped to 0; B (w1t) is zero-padded there,
// so the garbage contributes 0. 64 KB LDS -> 2 blocks/CU, 512 blocks.
// ---------------------------------------------------------------------------
__global__ __launch_bounds__(256)
void gemm1_f32(const float* __restrict__ x, const _Float16* __restrict__ B,
               const float* __restrict__ bias, _Float16* __restrict__ C) {
  __shared__ uint4 As[16 * 128];   // 32 KB: [q4][row], q4 = 4 f32 k-values
  __shared__ uint4 Bs[8 * 256];    // 32 KB: [q8][col], q8 = 8 f16 k-values
  const int t    = threadIdx.x;
  const int lane = t & 63;
  const int wave = t >> 6;         // WM=1, WN=4: wn = wave
  const int row0 = blockIdx.x * 128;
  const int l15  = lane & 15;
  const int lq   = lane >> 4;

  f32x4 acc[8][4];
#pragma unroll
  for (int i = 0; i < 8; ++i)
#pragma unroll
    for (int j = 0; j < 4; ++j) acc[i][j] = (f32x4){0.f, 0.f, 0.f, 0.f};

  for (int k0 = 0; k0 < IN_PAD; k0 += 64) {
    // A: 2048 16B slots (f32x4), 8 per thread
#pragma unroll
    for (int i = 0; i < 8; ++i) {
      const int c = i * 256 + t;
      const int q = c >> 7;        // 0..15
      const int r = c & 127;
      int kb = k0 + q * 4;
      if (kb >= IN_DIM) kb = 0;    // tail: B zero-pads k>=500
      gload_lds16(x + (size_t)(row0 + r) * IN_DIM + kb, As + q * 128 + r);
    }
    // B: 2048 16B slots (f16x8), 8 per thread
#pragma unroll
    for (int i = 0; i < 8; ++i) {
      const int c = i * 256 + t;
      const int q = c >> 8;        // 0..7
      const int r = c & 255;
      gload_lds16(B + (size_t)r * IN_PAD + (k0 + q * 8), Bs + q * 256 + r);
    }
    __syncthreads();
#pragma unroll
    for (int kk = 0; kk < 2; ++kk) {
      const int qa = kk * 4 + lq;  // k-octet 0..7
      half8 bfr[4];
#pragma unroll
      for (int nt = 0; nt < 4; ++nt)
        bfr[nt] = *((const half8*)(Bs + qa * 256 + wave * 64 + nt * 16 + l15));
#pragma unroll
      for (int mt = 0; mt < 8; ++mt) {
        const uint4 lo = As[(qa * 2 + 0) * 128 + mt * 16 + l15];
        const uint4 hi = As[(qa * 2 + 1) * 128 + mt * 16 + l15];
        half8 af;
        fp16x2 p;
        p = __builtin_amdgcn_cvt_pkrtz(uaf(lo.x), uaf(lo.y));
        af[0] = p[0]; af[1] = p[1];
        p = __builtin_amdgcn_cvt_pkrtz(uaf(lo.z), uaf(lo.w));
        af[2] = p[0]; af[3] = p[1];
        p = __builtin_amdgcn_cvt_pkrtz(uaf(hi.x), uaf(hi.y));
        af[4] = p[0]; af[5] = p[1];
        p = __builtin_amdgcn_cvt_pkrtz(uaf(hi.z), uaf(hi.w));
        af[6] = p[0]; af[7] = p[1];
#pragma unroll
        for (int nt = 0; nt < 4; ++nt)
          acc[mt][nt] = __builtin_amdgcn_mfma_f32_16x16x32_f16(
              af, bfr[nt], acc[mt][nt], 0, 0, 0);
      }
    }
    __syncthreads();
  }

#pragma unroll
  for (int mt = 0; mt < 8; ++mt) {
#pragma unroll
    for (int nt = 0; nt < 4; ++nt) {
      const int col = wave * 64 + nt * 16 + l15;
      const float bv = bias[col];
#pragma unroll
      for (int r = 0; r < 4; ++r) {
        const int row = row0 + mt * 16 + lq * 4 + r;
        const float v = fmaxf(acc[mt][nt][r] + bv, 0.f);
        C[(size_t)row * HID_DIM + col] = (_Float16)v;
      }
    }
  }
}

// ---- cast + transpose weight: W[K,N] fp32 -> Wt[N,Kpad] f16 ----------------
__global__ void cast_w_kernel(const float* __restrict__ W,
                              _Float16* __restrict__ Wt, int K, int Kpad,
                              int Nn) {
  const int idx = blockIdx.x * blockDim.x + threadIdx.x;
  if (idx >= Nn * Kpad) return;
  const int n = idx / Kpad;
  const int k = idx % Kpad;
  const float v = (k < K) ? W[(size_t)k * Nn + n] : 0.f;
  Wt[idx] = (_Float16)v;
}

// ---- CSR build: chunked counting sort (low-contention atomics) -------------
__global__ void hist2_kernel(const int* __restrict__ row,
                             int* __restrict__ cnt2, int* __restrict__ rank,
                             int E) {
  const int e = blockIdx.x * blockDim.x + threadIdx.x;
  if (e < E)
    rank[e] = atomicAdd(&cnt2[(e >> 16) * N_NODES + row[e]], 1);
}

__global__ void scan_tot_kernel(const int* __restrict__ cnt2,
                                int* __restrict__ tot) {
  const int r = blockIdx.x * blockDim.x + threadIdx.x;
  int s = 0;
#pragma unroll
  for (int c = 0; c < NCHUNK; ++c) s += cnt2[c * N_NODES + r];
  tot[r] = s;
}

// single-block exclusive scan of tot -> rowptr
__global__ void scan_kernel(const int4* __restrict__ counts4,
                            int* __restrict__ rowptr) {
  __shared__ int part[1024];
  const int t = threadIdx.x;
  const int base = t * 16;  // int4 units; 64 ints per thread
  int4 c[16];
  int s = 0;
#pragma unroll
  for (int i = 0; i < 16; ++i) {
    c[i] = counts4[base + i];
    s += c[i].x + c[i].y + c[i].z + c[i].w;
  }
  part[t] = s;
  __syncthreads();
  for (int off = 1; off < 1024; off <<= 1) {
    const int v = (t >= off) ? part[t - off] : 0;
    __syncthreads();
    part[t] += v;
    __syncthreads();
  }
  int run = (t == 0) ? 0 : part[t - 1];
#pragma unroll
  for (int i = 0; i < 16; ++i) {
    int4 r;
    r.x = run; run += c[i].x;
    r.y = run; run += c[i].y;
    r.z = run; run += c[i].z;
    r.w = run; run += c[i].w;
    ((int4*)rowptr)[base + i] = r;
  }
  if (t == 1023) rowptr[N_NODES] = run;
}

// cnt2[c][r] <- rowptr[r] + prefix_c(cnt2[.][r])   (in place, per-column)
__global__ void chunkbase_kernel(int* __restrict__ cnt2,
                                 const int* __restrict__ rowptr) {
  const int r = blockIdx.x * blockDim.x + threadIdx.x;
  int run = rowptr[r];
#pragma unroll
  for (int c = 0; c < NCHUNK; ++c) {
    const int t = cnt2[c * N_NODES + r];
    cnt2[c * N_NODES + r] = run;
    run += t;
  }
}

// atomic-free scatter: pos = chunkbase + rank
__global__ void scatter2_kernel(const int* __restrict__ row,
                                const int* __restrict__ col,
                                const float* __restrict__ w,
                                const int* __restrict__ rank,
                                const int* __restrict__ cbase,
                                int2* __restrict__ edges, int E) {
  const int e = blockIdx.x * blockDim.x + threadIdx.x;
  if (e < E) {
    const int pos = cbase[(e >> 16) * N_NODES + row[e]] + rank[e];
    edges[pos] = make_int2(col[e], __float_as_int(w[e]));
  }
}

// ---- propagation: pair-gather (2 edges per dword load) — R8, unchanged -----
template <bool OUT_F32>
__global__ __launch_bounds__(256)
void prop_step(const unsigned short* __restrict__ hin,
               const unsigned short* __restrict__ h0,
               void* __restrict__ hout, const int* __restrict__ rowptr,
               const int2* __restrict__ edges) {
  __shared__ int2 eb[4][CAPW];
  const int wave = threadIdx.x >> 6;
  const int lane = threadIdx.x & 63;
  const int half = lane >> 5;
  const int lp   = lane & 31;
  const int node0 = (blockIdx.x * 4 + wave) * NPW;
  const unsigned* __restrict__ hin32 = (const unsigned*)hin;
  const unsigned* __restrict__ h032  = (const unsigned*)h0;

  const int rp  = rowptr[node0 + min(lane, NPW)];
  const int beg = __shfl(rp, 0);
  const int nE  = __shfl(rp, NPW) - beg;
  const int rrel = rp - beg;
  int2* __restrict__ ebw = eb[wave];

  const bool fast = (nE <= CAPW);
  if (fast) {
    for (int i = lane; i < nE; i += 64) ebw[i] = edges[beg + i];
    __builtin_amdgcn_s_waitcnt(0);  // drain vm+lgkm: staging visible wave-wide
  }

  for (int i = 0; i < NPW; ++i) {
    const int nb = __shfl(rrel, i);
    const int ne = __shfl(rrel, i + 1);
    float ax0 = 0.f, ay0 = 0.f, ax1 = 0.f, ay1 = 0.f;
    int j = nb;
    if (fast) {
      for (; j + 8 <= ne; j += 8) {  // 4 pairs = 8 edges, 4 dword gathers
        const int2 e0 = ebw[j + 0 + half];
        const int2 e1 = ebw[j + 2 + half];
        const int2 e2 = ebw[j + 4 + half];
        const int2 e3 = ebw[j + 6 + half];
        const unsigned v0 = hin32[(e0.x << 5) | lp];
        const unsigned v1 = hin32[(e1.x << 5) | lp];
        const unsigned v2 = hin32[(e2.x << 5) | lp];
        const unsigned v3 = hin32[(e3.x << 5) | lp];
        const float w0 = uaf(e0.y), w1 = uaf(e1.y);
        const float w2 = uaf(e2.y), w3 = uaf(e3.y);
        ax0 = fmaf(w0, lo16(v0), ax0); ay0 = fmaf(w0, hi16(v0), ay0);
        ax1 = fmaf(w1, lo16(v1), ax1); ay1 = fmaf(w1, hi16(v1), ay1);
        ax0 = fmaf(w2, lo16(v2), ax0); ay0 = fmaf(w2, hi16(v2), ay0);
        ax1 = fmaf(w3, lo16(v3), ax1); ay1 = fmaf(w3, hi16(v3), ay1);
      }
      for (; j + 2 <= ne; j += 2) {  // pair tail
        const int2 e = ebw[j + half];
        const unsigned v = hin32[(e.x << 5) | lp];
        const float w = uaf(e.y);
        ax0 = fmaf(w, lo16(v), ax0); ay0 = fmaf(w, hi16(v), ay0);
      }
      if (j < ne) {  // single leftover edge: lower half contributes
        const int2 e = ebw[j];
        const unsigned v = hin32[(e.x << 5) | lp];
        const float w = half ? 0.f : uaf(e.y);
        ax0 = fmaf(w, lo16(v), ax0); ay0 = fmaf(w, hi16(v), ay0);
      }
    } else {  // degenerate degree distribution: direct-global path
      for (; j < ne; j += 2) {
        const int idx = j + half;
        const int2 e = edges[beg + (idx < ne ? idx : ne - 1)];
        const float w = (idx < ne) ? uaf(e.y) : 0.f;
        const unsigned v = hin32[(e.x << 5) | lp];
        ax0 = fmaf(w, lo16(v), ax0); ay0 = fmaf(w, hi16(v), ay0);
      }
    }
    float sx = ax0 + ax1;
    float sy = ay0 + ay1;
    sx += __shfl_xor(sx, 32);  // merge even/odd edge halves
    sy += __shfl_xor(sy, 32);
    const int o32 = ((node0 + i) << 5) | lp;
    const unsigned h0v = h032[o32];
    const float r0 = 0.9f * sx + 0.1f * lo16(h0v);
    const float r1 = 0.9f * sy + 0.1f * hi16(h0v);
    if (half == 0) {
      if (OUT_F32) {
        ((float2*)hout)[o32] = make_float2(r0, r1);
      } else {
        ((unsigned*)hout)[o32] =
            (unsigned)f2bf_rne(r0) | ((unsigned)f2bf_rne(r1) << 16);
      }
    }
  }
}

// ---------------------------------------------------------------------------
extern "C" void kernel_launch(void* const* d_in, const int* in_sizes, int n_in,
                              void* d_out, int out_size, void* d_ws,
                              size_t ws_size, hipStream_t stream) {
  const float* x  = (const float*)d_in[0];
  const float* W1 = (const float*)d_in[1];
  const float* b1 = (const float*)d_in[2];
  const float* W2 = (const float*)d_in[3];
  const float* b2 = (const float*)d_in[4];
  const float* W3 = (const float*)d_in[5];
  const float* b3 = (const float*)d_in[6];
  const float* ew = (const float*)d_in[7];
  const int* erow = (const int*)d_in[8];
  const int* ecol = (const int*)d_in[9];

  char* ws = (char*)d_ws;
  _Float16* h1  = (_Float16*)(ws + H1_OFF);
  _Float16* h2  = (_Float16*)(ws + H2_OFF);
  _Float16* w1t = (_Float16*)(ws + W1T_OFF);
  _Float16* w2t = (_Float16*)(ws + W2T_OFF);
  _Float16* w3t = (_Float16*)(ws + W3T_OFF);
  unsigned short* h0b = (unsigned short*)(ws + H0_OFF);
  unsigned short* hAb = (unsigned short*)(ws + HA_OFF);
  unsigned short* hBb = (unsigned short*)(ws + HB_OFF);
  int* rowp     = (int*)(ws + ROWP_OFF);
  int* cnt2     = (int*)(ws + CNT2_OFF);
  int* rankb    = (int*)(ws + RANK_OFF);
  int* tot      = (int*)(ws + TOT_OFF);
  int2* edges   = (int2*)(ws + EDG_OFF);
  float* outp   = (float*)d_out;

  // --- CSR build (chunked counting sort; scratch in H2 region) -------------
  hipMemsetAsync(cnt2, 0, NCHUNK * N_NODES * sizeof(int), stream);
  hist2_kernel<<<N_EDGES / 256, 256, 0, stream>>>(erow, cnt2, rankb, N_EDGES);
  scan_tot_kernel<<<N_NODES / 256, 256, 0, stream>>>(cnt2, tot);
  scan_kernel<<<1, 1024, 0, stream>>>((const int4*)tot, rowp);
  chunkbase_kernel<<<N_NODES / 256, 256, 0, stream>>>(cnt2, rowp);
  scatter2_kernel<<<N_EDGES / 256, 256, 0, stream>>>(erow, ecol, ew, rankb,
                                                     cnt2, edges, N_EDGES);

  // --- MLP ------------------------------------------------------------------
  cast_w_kernel<<<(HID_DIM * IN_PAD) / 256, 256, 0, stream>>>(W1, w1t, IN_DIM,
                                                              IN_PAD, HID_DIM);
  cast_w_kernel<<<(HID_DIM * HID_DIM) / 256, 256, 0, stream>>>(
      W2, w2t, HID_DIM, HID_DIM, HID_DIM);
  cast_w_kernel<<<(OUT_DIM * HID_DIM) / 256, 256, 0, stream>>>(
      W3, w3t, HID_DIM, HID_DIM, OUT_DIM);

  gemm1_f32<<<dim3(N_NODES / 128), 256, 0, stream>>>(x, w1t, b1, h1);
  gemm_kernel<128, 128, 2, 2, true, 0>
      <<<dim3(N_NODES / 128, HID_DIM / 128), 256, 0, stream>>>(
          h1, w2t, b2, h2, N_NODES, HID_DIM, HID_DIM);
  gemm_kernel<256, 64, 4, 1, false, 1>
      <<<dim3(N_NODES / 256, 1), 256, 0, stream>>>(h2, w3t, b3, h0b, N_NODES,
                                                   OUT_DIM, HID_DIM);

  // --- K=10 propagation (bf16 state; last step writes f32 to d_out) --------
  for (int s = 0; s < K_STEPS - 1; ++s) {
    const unsigned short* hin = (s == 0) ? h0b : ((s - 1) & 1 ? hBb : hAb);
    unsigned short* hout = (s & 1) ? hBb : hAb;
    prop_step<false><<<N_NODES / (4 * NPW), 256, 0, stream>>>(hin, h0b, hout,
                                                              rowp, edges);
  }
  prop_step<true><<<N_NODES / (4 * NPW), 256, 0, stream>>>(
      (K_STEPS - 2) & 1 ? hBb : hAb, h0b, outp, rowp, edges);
}